// Round 13
// baseline (782.472 us; speedup 1.0000x reference)
//
#include <hip/hip_runtime.h>

#define N_NODES 100000
#define E_EDGES 1600000
#define F_IN    64
#define H_DIM   128
#define R_REL   20
#define G_GRAPHS 64
#define C_CLASSES 10
#define L_LAYERS 2
#define BN_EPS  1e-5f
#define RN      (R_REL * N_NODES)   // 2,000,000 (rel,dst) bins

typedef unsigned short u16;
typedef unsigned int   u32;
typedef __attribute__((ext_vector_type(8))) short short8;
typedef __attribute__((ext_vector_type(4))) float f32x4;

typedef const __attribute__((address_space(1))) u32* gas_u32p;
typedef __attribute__((address_space(3))) u32* las_u32p;

static __device__ __forceinline__ float bf2f(u16 u) {
    u32 b = ((u32)u) << 16;
    return __builtin_bit_cast(float, b);
}
static __device__ __forceinline__ u16 f2bf(float f) {
    u32 x = __builtin_bit_cast(u32, f);
    u32 r = x + 0x7fff + ((x >> 16) & 1);   // RNE; inputs finite
    return (u16)(r >> 16);
}

// ============================================================
// Edge preprocessing: histogram+rank, scan, atomic-free scatter (R12, verified)
// ============================================================

__global__ void count_kernel(const int* __restrict__ ei, const int* __restrict__ et,
                             int* __restrict__ hist, int* __restrict__ erank) {
    for (int e = blockIdx.x * blockDim.x + threadIdx.x; e < E_EDGES;
         e += gridDim.x * blockDim.x) {
        int t = et[e];
        int d = ei[E_EDGES + e];
        erank[e] = atomicAdd(&hist[t * N_NODES + d], 1);
    }
}

__global__ void scan1_kernel(const int* __restrict__ in, int* __restrict__ out,
                             int* __restrict__ part, int n) {
    __shared__ int s[256];
    int t = threadIdx.x;
    int base = blockIdx.x * 1024;
    int v[4]; int sum = 0;
#pragma unroll
    for (int j = 0; j < 4; ++j) {
        int i = base + t * 4 + j;
        v[j] = (i < n) ? in[i] : 0;
        sum += v[j];
    }
    s[t] = sum;
    __syncthreads();
    for (int off = 1; off < 256; off <<= 1) {
        int x = (t >= off) ? s[t - off] : 0;
        __syncthreads();
        s[t] += x;
        __syncthreads();
    }
    if (t == 255) part[blockIdx.x] = s[255];
    int run = s[t] - sum;
#pragma unroll
    for (int j = 0; j < 4; ++j) {
        int i = base + t * 4 + j;
        if (i < n) out[i] = run;
        run += v[j];
    }
}

__global__ void scan2_kernel(int* __restrict__ part, int nb) {
    __shared__ int s[256];
    int t = threadIdx.x;
    int loc[8]; int sum = 0;
#pragma unroll
    for (int j = 0; j < 8; ++j) {
        int i = t * 8 + j;
        loc[j] = (i < nb) ? part[i] : 0;
        sum += loc[j];
    }
    s[t] = sum;
    __syncthreads();
    for (int off = 1; off < 256; off <<= 1) {
        int x = (t >= off) ? s[t - off] : 0;
        __syncthreads();
        s[t] += x;
        __syncthreads();
    }
    int run = s[t] - sum;
#pragma unroll
    for (int j = 0; j < 8; ++j) {
        int i = t * 8 + j;
        if (i < nb) part[i] = run;
        run += loc[j];
    }
}

__global__ void scan3_kernel(int* __restrict__ out, const int* __restrict__ part, int n) {
    for (int i = blockIdx.x * blockDim.x + threadIdx.x; i < n;
         i += gridDim.x * blockDim.x)
        out[i] += part[i >> 10];
    if (blockIdx.x == 0 && threadIdx.x == 0) out[n] = E_EDGES;
}

__global__ void bucket_kernel(const int* __restrict__ ei, const int* __restrict__ et,
                              const int* __restrict__ off2, const int* __restrict__ erank,
                              int2* __restrict__ epair) {
    for (int e = blockIdx.x * blockDim.x + threadIdx.x; e < E_EDGES;
         e += gridDim.x * blockDim.x) {
        int t = et[e];
        int s = ei[e];
        int d = ei[E_EDGES + e];
        epair[off2[t * N_NODES + d] + erank[e]] = make_int2(s, d);
    }
}

// ============================================================
// Weight pack: fp32 [K,128] -> bf16 MFMA-frag order (verified R2-R12)
// ============================================================
template<int K>
__global__ void pack_w(const float* __restrict__ W, u16* __restrict__ Wp) {
    const float* w = W + (size_t)blockIdx.x * K * H_DIM;
    u16* p = Wp + (size_t)blockIdx.x * K * H_DIM;
    for (int o = threadIdx.x; o < K * H_DIM; o += blockDim.x) {
        int j  = o & 7;
        int l  = (o >> 3) & 63;
        int ct = (o >> 9) & 7;
        int kt = o >> 12;
        int k  = kt * 32 + (l >> 4) * 8 + j;
        int n  = ct * 16 + (l & 15);
        p[o] = f2bf(w[(size_t)k * H_DIM + n]);
    }
}

__global__ void cvt_bf16_kernel(const float* __restrict__ in, u16* __restrict__ out, int n4) {
    for (int i = blockIdx.x * blockDim.x + threadIdx.x; i < n4;
         i += gridDim.x * blockDim.x) {
        float4 v = ((const float4*)in)[i];
        ushort4 o;
        o.x = f2bf(v.x); o.y = f2bf(v.y); o.z = f2bf(v.z); o.w = f2bf(v.w);
        ((ushort4*)out)[i] = o;
    }
}

// ============================================================
// Dense MFMA GEMM (input MLP) — proven R2-R12 structure
// ============================================================
template<int K, bool RELU, bool HASBIAS, bool OUTBF16>
__global__ __launch_bounds__(256)
void mfma_dense(const u16* __restrict__ A, const u16* __restrict__ Wp,
                const float* __restrict__ bias, void* __restrict__ OutV, int M) {
    constexpr int CH = K / 8;
    __shared__ u16 Ws[K * H_DIM];
    __shared__ u16 As[64 * H_DIM];

    for (int o = threadIdx.x; o < K * H_DIM / 8; o += 256)
        ((short8*)Ws)[o] = ((const short8*)Wp)[o];

    const int lane = threadIdx.x & 63;
    const int wave = threadIdx.x >> 6;
    const int l15  = lane & 15;
    const int kgrp = lane >> 4;
    const int arow = wave * 16 + l15;

    for (int tb = blockIdx.x * 64; tb < M; tb += gridDim.x * 64) {
        __syncthreads();
        for (int o = threadIdx.x; o < 64 * CH; o += 256) {
            int row = o / CH, cc = o % CH;
            int grow = tb + row;
            short8 v = {0,0,0,0,0,0,0,0};
            if (grow < M) v = *(const short8*)&A[(size_t)grow * K + cc * 8];
            *(short8*)&As[row * K + ((cc ^ (row & 7)) * 8)] = v;
        }
        __syncthreads();

        f32x4 acc[8];
#pragma unroll
        for (int i = 0; i < 8; ++i) {
            acc[i][0] = 0.f; acc[i][1] = 0.f; acc[i][2] = 0.f; acc[i][3] = 0.f;
        }
#pragma unroll
        for (int kt = 0; kt < K / 32; ++kt) {
            short8 af = *(const short8*)&As[arow * K + (((kt * 4 + kgrp) ^ (arow & 7)) * 8)];
#pragma unroll
            for (int ct = 0; ct < 8; ++ct) {
                short8 bf = *(const short8*)&Ws[(((kt * 8 + ct) * 64) + lane) * 8];
                acc[ct] = __builtin_amdgcn_mfma_f32_16x16x32_bf16(af, bf, acc[ct], 0, 0, 0);
            }
        }

        if (OUTBF16) {
            __syncthreads();
#pragma unroll
            for (int ct = 0; ct < 8; ++ct) {
#pragma unroll
                for (int r = 0; r < 4; ++r) {
                    int row = wave * 16 + kgrp * 4 + r;
                    int col = ct * 16 + l15;
                    float v = acc[ct][r];
                    if (HASBIAS) v += bias[col];
                    if (RELU)    v = fmaxf(v, 0.f);
                    As[row * H_DIM + ((((col >> 3) ^ (row & 7)) << 3) | (col & 7))] = f2bf(v);
                }
            }
            __syncthreads();
            u16* Out = (u16*)OutV;
            for (int o = threadIdx.x; o < 64 * 16; o += 256) {
                int row = o >> 4, cc = o & 15;
                int grow = tb + row;
                if (grow < M)
                    *(short8*)&Out[(size_t)grow * H_DIM + cc * 8] =
                        *(const short8*)&As[row * H_DIM + ((cc ^ (row & 7)) << 3)];
            }
        } else {
            float* Out = (float*)OutV;
#pragma unroll
            for (int ct = 0; ct < 8; ++ct) {
#pragma unroll
                for (int r = 0; r < 4; ++r) {
                    int grow = tb + wave * 16 + kgrp * 4 + r;
                    if (grow < M) {
                        float v = acc[ct][r];
                        if (HASBIAS) v += bias[ct * 16 + l15];
                        if (RELU)    v = fmaxf(v, 0.f);
                        Out[(size_t)grow * H_DIM + ct * 16 + l15] = v;
                    }
                }
            }
        }
    }
}

// ============================================================
// Fused RGCN conv (v8): R10/R12 structure + gather via
// __builtin_amdgcn_global_load_lds DMA: 16 edge-rows per batch staged
// global->LDS with ZERO VGPR cost (regalloc cannot serialize it),
// one vmcnt(0) exposure per batch. Edge pairs via uniform scalar loads.
// Barrier-free relation loop; B direct from global (L2-hot); BN fused.
// ============================================================
__global__ __launch_bounds__(256, 4)
void rgcn_conv(const u16* __restrict__ h, const u16* __restrict__ Wrel,
               const u16* __restrict__ Wroot, const float* __restrict__ bias,
               const int2* __restrict__ epair, const int* __restrict__ off2,
               float* __restrict__ outb, float* __restrict__ bn_sums) {
    __shared__ int offs[R_REL][65];
    __shared__ u16 Abf[64 * H_DIM];        // 16 KB; wave-private 16-row stripes
    __shared__ u32 stage[4][16 * 64];      // 16 KB; per-wave DMA staging (16 edges x 256B)
    __shared__ float bnS[H_DIM], bnSS[H_DIM];

    const int d0 = blockIdx.x * 64;
    for (int i = threadIdx.x; i < R_REL * 65; i += 256) {
        int r = i / 65, j = i % 65;
        offs[r][j] = off2[r * N_NODES + min(d0 + j, N_NODES)];
    }
    if (threadIdx.x < H_DIM) { bnS[threadIdx.x] = 0.f; bnSS[threadIdx.x] = 0.f; }

    const int lane = threadIdx.x & 63;
    const int wv   = threadIdx.x >> 6;     // 0..3
    const int l15  = lane & 15;
    const int kgrp = lane >> 4;
    const int arow = wv * 16 + l15;        // 0..63
    const u32* h2  = (const u32*)h;
    u32* Ab32 = (u32*)Abf;
    u32* mystage = stage[wv];

    f32x4 acc[8];
#pragma unroll
    for (int i = 0; i < 8; ++i) {
        acc[i][0] = 0.f; acc[i][1] = 0.f; acc[i][2] = 0.f; acc[i][3] = 0.f;
    }

    auto flushrow = [&](int dcur, int cnt, float f0, float f1) {
        float nm = 1.0f / (float)cnt;
        int dr = dcur - d0;
        u32 pk = (u32)f2bf(f0 * nm) | ((u32)f2bf(f1 * nm) << 16);
        Ab32[dr * 64 + ((((lane >> 2) ^ (dr & 7)) << 2) | (lane & 3))] = pk;
    };

    __syncthreads();      // offs + bnS init visible (only barrier before epilogue)

    int dd[16];
    // issue one 16-edge batch of global->LDS DMAs (no VGPR held across)
    auto stage_batch = [&](int e, int last) {
#pragma unroll
        for (int j = 0; j < 16; ++j) {
            int2 pr = epair[min(e + j, last)];   // uniform -> scalar load
            dd[j] = pr.y;
            const u32* g = h2 + (size_t)pr.x * 64 + lane;
            __builtin_amdgcn_global_load_lds((gas_u32p)g, (las_u32p)&mystage[j * 64],
                                             4, 0, 0);
        }
    };

    for (int r = 0; r < R_REL; ++r) {
        const int estart = __builtin_amdgcn_readfirstlane(offs[r][wv * 16]);
        const int eend   = __builtin_amdgcn_readfirstlane(offs[r][wv * 16 + 16]);
        if (eend <= estart) continue;      // wave-private skip
        const int last = eend - 1;

        // issue first batch, then zero stripe while DMAs fly
        stage_batch(estart, last);
#pragma unroll
        for (int i = 0; i < 16; ++i)
            Ab32[(wv * 16 + i) * 64 + lane] = 0u;

        int dcur = -1, cnt = 0;
        float f0 = 0.f, f1 = 0.f;
        for (int e = estart; e < eend; e += 16) {
            asm volatile("s_waitcnt vmcnt(0)" ::: "memory");
#pragma unroll
            for (int j = 0; j < 16; ++j) {
                if (e + j < eend) {                  // wave-uniform
                    u32 v = mystage[j * 64 + lane];
                    if (dd[j] != dcur) {
                        if (dcur >= 0) flushrow(dcur, cnt, f0, f1);
                        dcur = dd[j]; f0 = 0.f; f1 = 0.f; cnt = 0;
                    }
                    f0 += bf2f((u16)(v & 0xffff));
                    f1 += bf2f((u16)(v >> 16));
                    cnt++;
                }
            }
            if (e + 16 < eend) stage_batch(e + 16, last);   // overflow (rare)
        }
        if (dcur >= 0) flushrow(dcur, cnt, f0, f1);

        // ---- MFMA: A from my LDS stripe, B direct from global (L2-hot) ----
        const u16* Wr = Wrel + (size_t)r * H_DIM * H_DIM;
#pragma unroll
        for (int kt = 0; kt < 4; ++kt) {
            short8 af = *(const short8*)&Abf[arow * H_DIM + (((kt * 4 + kgrp) ^ (arow & 7)) * 8)];
#pragma unroll
            for (int ct = 0; ct < 8; ++ct) {
                short8 bf = *(const short8*)&Wr[(((kt * 8 + ct) * 64) + lane) * 8];
                acc[ct] = __builtin_amdgcn_mfma_f32_16x16x32_bf16(af, bf, acc[ct], 0, 0, 0);
            }
        }
    }

    // ---- root "relation": dense A = h rows direct from global ----
    {
        const int hrow = min(d0 + arow, N_NODES - 1);
#pragma unroll
        for (int kt = 0; kt < 4; ++kt) {
            short8 af = *(const short8*)&h[(size_t)hrow * H_DIM + kt * 32 + kgrp * 8];
#pragma unroll
            for (int ct = 0; ct < 8; ++ct) {
                short8 bf = *(const short8*)&Wroot[(((kt * 8 + ct) * 64) + lane) * 8];
                acc[ct] = __builtin_amdgcn_mfma_f32_16x16x32_bf16(af, bf, acc[ct], 0, 0, 0);
            }
        }
    }

    // ---- epilogue: outb = acc + bias; fused BN sum/sumsq ----
#pragma unroll
    for (int ct = 0; ct < 8; ++ct) {
        float bv = bias[ct * 16 + l15];
        float sl = 0.f, sq = 0.f;
#pragma unroll
        for (int rr = 0; rr < 4; ++rr) {
            int grow = d0 + wv * 16 + kgrp * 4 + rr;
            if (grow < N_NODES) {
                float v = acc[ct][rr] + bv;
                outb[(size_t)grow * H_DIM + ct * 16 + l15] = v;
                sl += v;
                sq += v * v;
            }
        }
        sl += __shfl_xor(sl, 16); sl += __shfl_xor(sl, 32);
        sq += __shfl_xor(sq, 16); sq += __shfl_xor(sq, 32);
        if (kgrp == 0) {
            atomicAdd(&bnS[ct * 16 + l15], sl);
            atomicAdd(&bnSS[ct * 16 + l15], sq);
        }
    }
    __syncthreads();
    if (threadIdx.x < H_DIM) {
        atomicAdd(&bn_sums[threadIdx.x], bnS[threadIdx.x]);
        atomicAdd(&bn_sums[H_DIM + threadIdx.x], bnSS[threadIdx.x]);
    }
}

// ============================================================
// BatchNorm apply + ReLU -> bf16 h
// ============================================================
__global__ void bn_apply(const float* __restrict__ X, const float* __restrict__ sums,
                         const float* __restrict__ gg, const float* __restrict__ bb,
                         u16* __restrict__ Hout) {
    __shared__ float sc[H_DIM], sh[H_DIM];
    if (threadIdx.x < H_DIM) {
        float mean = sums[threadIdx.x] * (1.0f / N_NODES);
        float var  = sums[H_DIM + threadIdx.x] * (1.0f / N_NODES) - mean * mean;
        float inv  = rsqrtf(var + BN_EPS) * gg[threadIdx.x];
        sc[threadIdx.x] = inv;
        sh[threadIdx.x] = bb[threadIdx.x] - mean * inv;
    }
    __syncthreads();
    int total = N_NODES * (H_DIM / 4);
    for (int idx = blockIdx.x * 256 + threadIdx.x; idx < total; idx += gridDim.x * 256) {
        float4 v = ((const float4*)X)[idx];
        int c = (idx & 31) << 2;
        ushort4 o;
        o.x = f2bf(fmaxf(v.x * sc[c + 0] + sh[c + 0], 0.f));
        o.y = f2bf(fmaxf(v.y * sc[c + 1] + sh[c + 1], 0.f));
        o.z = f2bf(fmaxf(v.z * sc[c + 2] + sh[c + 2], 0.f));
        o.w = f2bf(fmaxf(v.w * sc[c + 3] + sh[c + 3], 0.f));
        ((ushort4*)Hout)[idx] = o;
    }
}

// ============================================================
// Pool + classifier
// ============================================================
__global__ void pool_kernel(const u16* __restrict__ Hf, const int* __restrict__ batch,
                            float* __restrict__ pool, float* __restrict__ pcnt) {
    int col  = threadIdx.x & 127;
    int half = threadIdx.x >> 7;
    int chunk = (N_NODES + gridDim.x - 1) / gridDim.x;
    int start = blockIdx.x * chunk;
    int end   = min(N_NODES, start + chunk);
    int curg = -1;
    float acc = 0.f, c = 0.f;
    for (int row = start + half; row < end; row += 2) {
        int g = batch[row];
        if (g != curg) {
            if (curg >= 0) {
                atomicAdd(&pool[curg * H_DIM + col], acc);
                if (col == 0) atomicAdd(&pcnt[curg], c);
            }
            curg = g; acc = 0.f; c = 0.f;
        }
        acc += bf2f(Hf[(size_t)row * H_DIM + col]);
        c += 1.f;
    }
    if (curg >= 0) {
        atomicAdd(&pool[curg * H_DIM + col], acc);
        if (col == 0) atomicAdd(&pcnt[curg], c);
    }
}

__global__ void logits_kernel(const float* __restrict__ pool, const float* __restrict__ pcnt,
                              const float* __restrict__ w_out, const float* __restrict__ b_out,
                              float* __restrict__ out) {
    int g = blockIdx.x;
    __shared__ float p[H_DIM];
    float cnt = fmaxf(pcnt[g], 1.0f);
    p[threadIdx.x] = pool[g * H_DIM + threadIdx.x] / cnt;
    __syncthreads();
    if (threadIdx.x < C_CLASSES) {
        float acc = b_out[threadIdx.x];
        for (int k = 0; k < H_DIM; ++k)
            acc += p[k] * w_out[k * C_CLASSES + threadIdx.x];
        out[g * C_CLASSES + threadIdx.x] = 1.0f / (1.0f + expf(-acc));
    }
}

// ============================================================
// Host launch
// ============================================================
static inline size_t align256(size_t x) { return (x + 255) & ~(size_t)255; }

extern "C" void kernel_launch(void* const* d_in, const int* in_sizes, int n_in,
                              void* d_out, int out_size, void* d_ws, size_t ws_size,
                              hipStream_t stream) {
    const float* x      = (const float*)d_in[0];
    const int*   ei     = (const int*)d_in[1];
    const int*   et     = (const int*)d_in[2];
    const int*   batch  = (const int*)d_in[3];
    const float* w_in   = (const float*)d_in[4];
    const float* b_in   = (const float*)d_in[5];
    const float* rel_w  = (const float*)d_in[6];
    const float* root_w = (const float*)d_in[7];
    const float* conv_b = (const float*)d_in[8];
    const float* bn_g   = (const float*)d_in[9];
    const float* bn_b   = (const float*)d_in[10];
    const float* w_out  = (const float*)d_in[11];
    const float* b_out  = (const float*)d_in[12];
    float* out = (float*)d_out;

    char* ws = (char*)d_ws;
    size_t off = 0;
    u16*   h_bf  = (u16*)(ws + off);  off += align256((size_t)N_NODES * H_DIM * 2);
    float* outb  = (float*)(ws + off); off += align256((size_t)N_NODES * H_DIM * 4);
    u16*   x_bf  = (u16*)(ws + off);  off += align256((size_t)N_NODES * F_IN * 2);
    int*   off2  = (int*)(ws + off);  off += align256((size_t)(RN + 1) * 4 + 256);
    int*   hist  = (int*)(ws + off);  off += align256((size_t)RN * 4);
    int*   erank = (int*)(ws + off);  off += align256((size_t)E_EDGES * 4);
    int2*  e_pair = (int2*)(ws + off); off += align256((size_t)E_EDGES * 8 + 256);
    u16*   wp_in   = (u16*)(ws + off); off += align256((size_t)F_IN * H_DIM * 2);
    u16*   wp_root = (u16*)(ws + off); off += align256((size_t)L_LAYERS * H_DIM * H_DIM * 2);
    u16*   wp_rel  = (u16*)(ws + off); off += align256((size_t)L_LAYERS * R_REL * H_DIM * H_DIM * 2);
    int*   scan_part  = (int*)(ws + off); off += align256(2048 * 4);
    float* bn_sums    = (float*)(ws + off); off += align256(2 * H_DIM * 4);
    float* pool       = (float*)(ws + off); off += align256((size_t)G_GRAPHS * H_DIM * 4);
    float* pcnt       = (float*)(ws + off); off += 256;

    // ---- preprocessing: histogram+rank -> scan -> atomic-free scatter ----
    hipMemsetAsync(hist, 0, (size_t)RN * 4, stream);
    count_kernel<<<1024, 256, 0, stream>>>(ei, et, hist, erank);
    const int NB = (RN + 1023) / 1024;                   // 1954
    scan1_kernel<<<NB, 256, 0, stream>>>(hist, off2, scan_part, RN);
    scan2_kernel<<<1, 256, 0, stream>>>(scan_part, NB);
    scan3_kernel<<<2048, 256, 0, stream>>>(off2, scan_part, RN);
    bucket_kernel<<<2048, 256, 0, stream>>>(ei, et, off2, erank, e_pair);

    // ---- convert inputs / pack weights to bf16 ----
    cvt_bf16_kernel<<<2048, 256, 0, stream>>>(x, x_bf, N_NODES * F_IN / 4);
    pack_w<F_IN><<<1, 256, 0, stream>>>(w_in, wp_in);
    pack_w<H_DIM><<<L_LAYERS, 256, 0, stream>>>(root_w, wp_root);
    pack_w<H_DIM><<<L_LAYERS * R_REL, 256, 0, stream>>>(rel_w, wp_rel);

    // ---- input MLP: h = relu(x @ w_in + b_in) -> bf16 ----
    mfma_dense<F_IN, true, true, true><<<dim3(640), 256, 0, stream>>>(
        x_bf, wp_in, b_in, h_bf, N_NODES);

    // ---- RGCN layers (barrier-free fused conv, DMA-staged gather) ----
    const int CONV_BLOCKS = (N_NODES + 63) / 64;   // 1563
    for (int l = 0; l < L_LAYERS; ++l) {
        hipMemsetAsync(bn_sums, 0, 2 * H_DIM * 4, stream);
        rgcn_conv<<<dim3(CONV_BLOCKS), 256, 0, stream>>>(
            h_bf, wp_rel + (size_t)l * R_REL * H_DIM * H_DIM,
            wp_root + (size_t)l * H_DIM * H_DIM, conv_b + (size_t)l * H_DIM,
            e_pair, off2, outb, bn_sums);
        bn_apply<<<2048, 256, 0, stream>>>(outb, bn_sums,
                                           bn_g + (size_t)l * H_DIM,
                                           bn_b + (size_t)l * H_DIM, h_bf);
    }

    // ---- global mean pool + classifier ----
    hipMemsetAsync(pool, 0, (size_t)G_GRAPHS * H_DIM * 4, stream);
    hipMemsetAsync(pcnt, 0, 256, stream);
    pool_kernel<<<512, 256, 0, stream>>>(h_bf, batch, pool, pcnt);
    logits_kernel<<<G_GRAPHS, 128, 0, stream>>>(pool, pcnt, w_out, b_out, out);
}

// Round 14
// 746.153 us; speedup vs baseline: 1.0487x; 1.0487x over previous
//
#include <hip/hip_runtime.h>

#define N_NODES 100000
#define E_EDGES 1600000
#define F_IN    64
#define H_DIM   128
#define R_REL   20
#define G_GRAPHS 64
#define C_CLASSES 10
#define L_LAYERS 2
#define BN_EPS  1e-5f
#define RN      (R_REL * N_NODES)   // 2,000,000 (rel,dst) bins

typedef unsigned short u16;
typedef unsigned int   u32;
typedef __attribute__((ext_vector_type(8))) short short8;
typedef __attribute__((ext_vector_type(4))) float f32x4;

static __device__ __forceinline__ float bf2f(u16 u) {
    u32 b = ((u32)u) << 16;
    return __builtin_bit_cast(float, b);
}
static __device__ __forceinline__ u16 f2bf(float f) {
    u32 x = __builtin_bit_cast(u32, f);
    u32 r = x + 0x7fff + ((x >> 16) & 1);   // RNE; inputs finite
    return (u16)(r >> 16);
}

// ============================================================
// Edge preprocessing: histogram+rank, scan, atomic-free scatter (R12, verified)
// ============================================================

__global__ void count_kernel(const int* __restrict__ ei, const int* __restrict__ et,
                             int* __restrict__ hist, int* __restrict__ erank) {
    for (int e = blockIdx.x * blockDim.x + threadIdx.x; e < E_EDGES;
         e += gridDim.x * blockDim.x) {
        int t = et[e];
        int d = ei[E_EDGES + e];
        erank[e] = atomicAdd(&hist[t * N_NODES + d], 1);
    }
}

__global__ void scan1_kernel(const int* __restrict__ in, int* __restrict__ out,
                             int* __restrict__ part, int n) {
    __shared__ int s[256];
    int t = threadIdx.x;
    int base = blockIdx.x * 1024;
    int v[4]; int sum = 0;
#pragma unroll
    for (int j = 0; j < 4; ++j) {
        int i = base + t * 4 + j;
        v[j] = (i < n) ? in[i] : 0;
        sum += v[j];
    }
    s[t] = sum;
    __syncthreads();
    for (int off = 1; off < 256; off <<= 1) {
        int x = (t >= off) ? s[t - off] : 0;
        __syncthreads();
        s[t] += x;
        __syncthreads();
    }
    if (t == 255) part[blockIdx.x] = s[255];
    int run = s[t] - sum;
#pragma unroll
    for (int j = 0; j < 4; ++j) {
        int i = base + t * 4 + j;
        if (i < n) out[i] = run;
        run += v[j];
    }
}

__global__ void scan2_kernel(int* __restrict__ part, int nb) {
    __shared__ int s[256];
    int t = threadIdx.x;
    int loc[8]; int sum = 0;
#pragma unroll
    for (int j = 0; j < 8; ++j) {
        int i = t * 8 + j;
        loc[j] = (i < nb) ? part[i] : 0;
        sum += loc[j];
    }
    s[t] = sum;
    __syncthreads();
    for (int off = 1; off < 256; off <<= 1) {
        int x = (t >= off) ? s[t - off] : 0;
        __syncthreads();
        s[t] += x;
        __syncthreads();
    }
    int run = s[t] - sum;
#pragma unroll
    for (int j = 0; j < 8; ++j) {
        int i = t * 8 + j;
        if (i < nb) part[i] = run;
        run += loc[j];
    }
}

__global__ void scan3_kernel(int* __restrict__ out, const int* __restrict__ part, int n) {
    for (int i = blockIdx.x * blockDim.x + threadIdx.x; i < n;
         i += gridDim.x * blockDim.x)
        out[i] += part[i >> 10];
    if (blockIdx.x == 0 && threadIdx.x == 0) out[n] = E_EDGES;
}

__global__ void bucket_kernel(const int* __restrict__ ei, const int* __restrict__ et,
                              const int* __restrict__ off2, const int* __restrict__ erank,
                              int2* __restrict__ epair) {
    for (int e = blockIdx.x * blockDim.x + threadIdx.x; e < E_EDGES;
         e += gridDim.x * blockDim.x) {
        int t = et[e];
        int s = ei[e];
        int d = ei[E_EDGES + e];
        epair[off2[t * N_NODES + d] + erank[e]] = make_int2(s, d);
    }
}

// ============================================================
// Weight pack (single launch): fp32 [K,128] -> bf16 MFMA-frag order
// block 0: w_in (K=64); blocks 1..2: root; blocks 3..42: rel
// ============================================================
__global__ void pack_all(const float* __restrict__ w_in, const float* __restrict__ root_w,
                         const float* __restrict__ rel_w, u16* __restrict__ wp_in,
                         u16* __restrict__ wp_root, u16* __restrict__ wp_rel) {
    int b = blockIdx.x;
    const float* w; u16* p; int K;
    if (b == 0)      { w = w_in;  p = wp_in;  K = F_IN; }
    else if (b <= 2) { w = root_w + (size_t)(b - 1) * H_DIM * H_DIM;
                       p = wp_root + (size_t)(b - 1) * H_DIM * H_DIM; K = H_DIM; }
    else             { w = rel_w + (size_t)(b - 3) * H_DIM * H_DIM;
                       p = wp_rel + (size_t)(b - 3) * H_DIM * H_DIM; K = H_DIM; }
    for (int o = threadIdx.x; o < K * H_DIM; o += blockDim.x) {
        int j  = o & 7;
        int l  = (o >> 3) & 63;
        int ct = (o >> 9) & 7;
        int kt = o >> 12;
        int k  = kt * 32 + (l >> 4) * 8 + j;
        int n  = ct * 16 + (l & 15);
        p[o] = f2bf(w[(size_t)k * H_DIM + n]);
    }
}

// ============================================================
// Dense MFMA GEMM (input MLP) — R2-R12 structure; INF32 stages fp32->bf16
// ============================================================
template<int K, bool INF32, bool RELU, bool HASBIAS, bool OUTBF16>
__global__ __launch_bounds__(256)
void mfma_dense(const void* __restrict__ Av, const u16* __restrict__ Wp,
                const float* __restrict__ bias, void* __restrict__ OutV, int M) {
    constexpr int CH = K / 8;
    __shared__ u16 Ws[K * H_DIM];
    __shared__ u16 As[64 * H_DIM];

    for (int o = threadIdx.x; o < K * H_DIM / 8; o += 256)
        ((short8*)Ws)[o] = ((const short8*)Wp)[o];

    const int lane = threadIdx.x & 63;
    const int wave = threadIdx.x >> 6;
    const int l15  = lane & 15;
    const int kgrp = lane >> 4;
    const int arow = wave * 16 + l15;

    for (int tb = blockIdx.x * 64; tb < M; tb += gridDim.x * 64) {
        __syncthreads();
        for (int o = threadIdx.x; o < 64 * CH; o += 256) {
            int row = o / CH, cc = o % CH;
            int grow = tb + row;
            short8 v = {0,0,0,0,0,0,0,0};
            if (grow < M) {
                if (INF32) {
                    const float* xf = (const float*)Av;
                    const float4* px = (const float4*)&xf[(size_t)grow * K + cc * 8];
                    float4 a = px[0], b = px[1];
                    v[0] = (short)f2bf(a.x); v[1] = (short)f2bf(a.y);
                    v[2] = (short)f2bf(a.z); v[3] = (short)f2bf(a.w);
                    v[4] = (short)f2bf(b.x); v[5] = (short)f2bf(b.y);
                    v[6] = (short)f2bf(b.z); v[7] = (short)f2bf(b.w);
                } else {
                    v = *(const short8*)&((const u16*)Av)[(size_t)grow * K + cc * 8];
                }
            }
            *(short8*)&As[row * K + ((cc ^ (row & 7)) * 8)] = v;
        }
        __syncthreads();

        f32x4 acc[8];
#pragma unroll
        for (int i = 0; i < 8; ++i) {
            acc[i][0] = 0.f; acc[i][1] = 0.f; acc[i][2] = 0.f; acc[i][3] = 0.f;
        }
#pragma unroll
        for (int kt = 0; kt < K / 32; ++kt) {
            short8 af = *(const short8*)&As[arow * K + (((kt * 4 + kgrp) ^ (arow & 7)) * 8)];
#pragma unroll
            for (int ct = 0; ct < 8; ++ct) {
                short8 bf = *(const short8*)&Ws[(((kt * 8 + ct) * 64) + lane) * 8];
                acc[ct] = __builtin_amdgcn_mfma_f32_16x16x32_bf16(af, bf, acc[ct], 0, 0, 0);
            }
        }

        if (OUTBF16) {
            __syncthreads();
#pragma unroll
            for (int ct = 0; ct < 8; ++ct) {
#pragma unroll
                for (int r = 0; r < 4; ++r) {
                    int row = wave * 16 + kgrp * 4 + r;
                    int col = ct * 16 + l15;
                    float v = acc[ct][r];
                    if (HASBIAS) v += bias[col];
                    if (RELU)    v = fmaxf(v, 0.f);
                    As[row * H_DIM + ((((col >> 3) ^ (row & 7)) << 3) | (col & 7))] = f2bf(v);
                }
            }
            __syncthreads();
            u16* Out = (u16*)OutV;
            for (int o = threadIdx.x; o < 64 * 16; o += 256) {
                int row = o >> 4, cc = o & 15;
                int grow = tb + row;
                if (grow < M)
                    *(short8*)&Out[(size_t)grow * H_DIM + cc * 8] =
                        *(const short8*)&As[row * H_DIM + ((cc ^ (row & 7)) << 3)];
            }
        } else {
            float* Out = (float*)OutV;
#pragma unroll
            for (int ct = 0; ct < 8; ++ct) {
#pragma unroll
                for (int r = 0; r < 4; ++r) {
                    int grow = tb + wave * 16 + kgrp * 4 + r;
                    if (grow < M) {
                        float v = acc[ct][r];
                        if (HASBIAS) v += bias[ct * 16 + l15];
                        if (RELU)    v = fmaxf(v, 0.f);
                        Out[(size_t)grow * H_DIM + ct * 16 + l15] = v;
                    }
                }
            }
        }
    }
}

// ============================================================
// Fused RGCN conv (v9): R12 wave-level logic, 32 dsts / 128 threads /
// 2 waves per block -> LDS ~12 KB -> ~13 blocks (26 waves) per CU.
// Gather TLP doubles; everything else verbatim from R12.
// ============================================================
__global__ __launch_bounds__(128, 8)
void rgcn_conv(const u16* __restrict__ h, const u16* __restrict__ Wrel,
               const u16* __restrict__ Wroot, const float* __restrict__ bias,
               const int2* __restrict__ epair, const int* __restrict__ off2,
               float* __restrict__ outb, float* __restrict__ bn_sums) {
    __shared__ int offs[R_REL][33];
    __shared__ u16 Abf[32 * H_DIM];        // 8 KB; wave-private 16-row stripes
    __shared__ float bnS[H_DIM], bnSS[H_DIM];

    const int d0 = blockIdx.x * 32;
    for (int i = threadIdx.x; i < R_REL * 33; i += 128) {
        int r = i / 33, j = i % 33;
        offs[r][j] = off2[r * N_NODES + min(d0 + j, N_NODES)];
    }
    bnS[threadIdx.x] = 0.f;                // 128 threads == H_DIM
    bnSS[threadIdx.x] = 0.f;

    const int lane = threadIdx.x & 63;
    const int wv   = threadIdx.x >> 6;     // 0..1
    const int l15  = lane & 15;
    const int kgrp = lane >> 4;
    const int arow = wv * 16 + l15;        // 0..31
    const u32* h2  = (const u32*)h;
    u32* Ab32 = (u32*)Abf;

    f32x4 acc[8];
#pragma unroll
    for (int i = 0; i < 8; ++i) {
        acc[i][0] = 0.f; acc[i][1] = 0.f; acc[i][2] = 0.f; acc[i][3] = 0.f;
    }

    auto flushrow = [&](int dcur, int cnt, float f0, float f1) {
        float nm = 1.0f / (float)cnt;
        int dr = dcur - d0;                // 0..31
        u32 pk = (u32)f2bf(f0 * nm) | ((u32)f2bf(f1 * nm) << 16);
        Ab32[dr * 64 + ((((lane >> 2) ^ (dr & 7)) << 2) | (lane & 3))] = pk;
    };

    __syncthreads();      // offs + bnS init visible (only barrier before epilogue)

    for (int r = 0; r < R_REL; ++r) {
        const int estart = __builtin_amdgcn_readfirstlane(offs[r][wv * 16]);
        const int eend   = __builtin_amdgcn_readfirstlane(offs[r][wv * 16 + 16]);
        if (eend <= estart) continue;      // wave-private skip

        // zero my stripe (wave-local)
#pragma unroll
        for (int i = 0; i < 16; ++i)
            Ab32[(wv * 16 + i) * 64 + lane] = 0u;

        // ---- 16-deep batched gather + run-length flush (R12-verified) ----
        {
            const int last = eend - 1;
            int ss[16], dd[16];
            u32 rv[16];
#pragma unroll
            for (int j = 0; j < 16; ++j) {
                int2 pr = epair[min(estart + j, last)];
                ss[j] = pr.x; dd[j] = pr.y;
            }
#pragma unroll
            for (int j = 0; j < 16; ++j)
                rv[j] = h2[(size_t)ss[j] * 64 + lane];

            int dcur = -1, cnt = 0;
            float f0 = 0.f, f1 = 0.f;
#pragma unroll
            for (int j = 0; j < 16; ++j) {
                if (estart + j < eend) {                 // wave-uniform
                    if (dd[j] != dcur) {
                        if (dcur >= 0) flushrow(dcur, cnt, f0, f1);
                        dcur = dd[j]; f0 = 0.f; f1 = 0.f; cnt = 0;
                    }
                    f0 += bf2f((u16)(rv[j] & 0xffff));
                    f1 += bf2f((u16)(rv[j] >> 16));
                    cnt++;
                }
            }
            // overflow batches (segment > 16 edges)
            for (int e = estart + 16; e < eend; e += 16) {
                int ss2[16], dd2[16];
                u32 rv2[16];
#pragma unroll
                for (int j = 0; j < 16; ++j) {
                    int2 pr = epair[min(e + j, last)];
                    ss2[j] = pr.x; dd2[j] = pr.y;
                }
#pragma unroll
                for (int j = 0; j < 16; ++j)
                    rv2[j] = h2[(size_t)ss2[j] * 64 + lane];
#pragma unroll
                for (int j = 0; j < 16; ++j) {
                    if (e + j < eend) {
                        if (dd2[j] != dcur) {
                            if (dcur >= 0) flushrow(dcur, cnt, f0, f1);
                            dcur = dd2[j]; f0 = 0.f; f1 = 0.f; cnt = 0;
                        }
                        f0 += bf2f((u16)(rv2[j] & 0xffff));
                        f1 += bf2f((u16)(rv2[j] >> 16));
                        cnt++;
                    }
                }
            }
            if (dcur >= 0) flushrow(dcur, cnt, f0, f1);
        }

        // ---- MFMA: A from my LDS stripe, B direct from global (L2-hot) ----
        const u16* Wr = Wrel + (size_t)r * H_DIM * H_DIM;
#pragma unroll
        for (int kt = 0; kt < 4; ++kt) {
            short8 af = *(const short8*)&Abf[arow * H_DIM + (((kt * 4 + kgrp) ^ (arow & 7)) * 8)];
#pragma unroll
            for (int ct = 0; ct < 8; ++ct) {
                short8 bf = *(const short8*)&Wr[(((kt * 8 + ct) * 64) + lane) * 8];
                acc[ct] = __builtin_amdgcn_mfma_f32_16x16x32_bf16(af, bf, acc[ct], 0, 0, 0);
            }
        }
    }

    // ---- root "relation": dense A = h rows direct from global ----
    {
        const int hrow = min(d0 + arow, N_NODES - 1);
#pragma unroll
        for (int kt = 0; kt < 4; ++kt) {
            short8 af = *(const short8*)&h[(size_t)hrow * H_DIM + kt * 32 + kgrp * 8];
#pragma unroll
            for (int ct = 0; ct < 8; ++ct) {
                short8 bf = *(const short8*)&Wroot[(((kt * 8 + ct) * 64) + lane) * 8];
                acc[ct] = __builtin_amdgcn_mfma_f32_16x16x32_bf16(af, bf, acc[ct], 0, 0, 0);
            }
        }
    }

    // ---- epilogue: outb = acc + bias; fused BN sum/sumsq ----
#pragma unroll
    for (int ct = 0; ct < 8; ++ct) {
        float bv = bias[ct * 16 + l15];
        float sl = 0.f, sq = 0.f;
#pragma unroll
        for (int rr = 0; rr < 4; ++rr) {
            int grow = d0 + wv * 16 + kgrp * 4 + rr;
            if (grow < N_NODES) {
                float v = acc[ct][rr] + bv;
                outb[(size_t)grow * H_DIM + ct * 16 + l15] = v;
                sl += v;
                sq += v * v;
            }
        }
        sl += __shfl_xor(sl, 16); sl += __shfl_xor(sl, 32);
        sq += __shfl_xor(sq, 16); sq += __shfl_xor(sq, 32);
        if (kgrp == 0) {
            atomicAdd(&bnS[ct * 16 + l15], sl);
            atomicAdd(&bnSS[ct * 16 + l15], sq);
        }
    }
    __syncthreads();
    atomicAdd(&bn_sums[threadIdx.x], bnS[threadIdx.x]);           // 128 == H_DIM
    atomicAdd(&bn_sums[H_DIM + threadIdx.x], bnSS[threadIdx.x]);
}

// ============================================================
// BatchNorm apply + ReLU -> bf16 h
// ============================================================
__global__ void bn_apply(const float* __restrict__ X, const float* __restrict__ sums,
                         const float* __restrict__ gg, const float* __restrict__ bb,
                         u16* __restrict__ Hout) {
    __shared__ float sc[H_DIM], sh[H_DIM];
    if (threadIdx.x < H_DIM) {
        float mean = sums[threadIdx.x] * (1.0f / N_NODES);
        float var  = sums[H_DIM + threadIdx.x] * (1.0f / N_NODES) - mean * mean;
        float inv  = rsqrtf(var + BN_EPS) * gg[threadIdx.x];
        sc[threadIdx.x] = inv;
        sh[threadIdx.x] = bb[threadIdx.x] - mean * inv;
    }
    __syncthreads();
    int total = N_NODES * (H_DIM / 4);
    for (int idx = blockIdx.x * 256 + threadIdx.x; idx < total; idx += gridDim.x * 256) {
        float4 v = ((const float4*)X)[idx];
        int c = (idx & 31) << 2;
        ushort4 o;
        o.x = f2bf(fmaxf(v.x * sc[c + 0] + sh[c + 0], 0.f));
        o.y = f2bf(fmaxf(v.y * sc[c + 1] + sh[c + 1], 0.f));
        o.z = f2bf(fmaxf(v.z * sc[c + 2] + sh[c + 2], 0.f));
        o.w = f2bf(fmaxf(v.w * sc[c + 3] + sh[c + 3], 0.f));
        ((ushort4*)Hout)[idx] = o;
    }
}

// ============================================================
// Pool + classifier
// ============================================================
__global__ void pool_kernel(const u16* __restrict__ Hf, const int* __restrict__ batch,
                            float* __restrict__ pool, float* __restrict__ pcnt) {
    int col  = threadIdx.x & 127;
    int half = threadIdx.x >> 7;
    int chunk = (N_NODES + gridDim.x - 1) / gridDim.x;
    int start = blockIdx.x * chunk;
    int end   = min(N_NODES, start + chunk);
    int curg = -1;
    float acc = 0.f, c = 0.f;
    for (int row = start + half; row < end; row += 2) {
        int g = batch[row];
        if (g != curg) {
            if (curg >= 0) {
                atomicAdd(&pool[curg * H_DIM + col], acc);
                if (col == 0) atomicAdd(&pcnt[curg], c);
            }
            curg = g; acc = 0.f; c = 0.f;
        }
        acc += bf2f(Hf[(size_t)row * H_DIM + col]);
        c += 1.f;
    }
    if (curg >= 0) {
        atomicAdd(&pool[curg * H_DIM + col], acc);
        if (col == 0) atomicAdd(&pcnt[curg], c);
    }
}

__global__ void logits_kernel(const float* __restrict__ pool, const float* __restrict__ pcnt,
                              const float* __restrict__ w_out, const float* __restrict__ b_out,
                              float* __restrict__ out) {
    int g = blockIdx.x;
    __shared__ float p[H_DIM];
    float cnt = fmaxf(pcnt[g], 1.0f);
    p[threadIdx.x] = pool[g * H_DIM + threadIdx.x] / cnt;
    __syncthreads();
    if (threadIdx.x < C_CLASSES) {
        float acc = b_out[threadIdx.x];
        for (int k = 0; k < H_DIM; ++k)
            acc += p[k] * w_out[k * C_CLASSES + threadIdx.x];
        out[g * C_CLASSES + threadIdx.x] = 1.0f / (1.0f + expf(-acc));
    }
}

// ============================================================
// Host launch
// ============================================================
static inline size_t align256(size_t x) { return (x + 255) & ~(size_t)255; }

extern "C" void kernel_launch(void* const* d_in, const int* in_sizes, int n_in,
                              void* d_out, int out_size, void* d_ws, size_t ws_size,
                              hipStream_t stream) {
    const float* x      = (const float*)d_in[0];
    const int*   ei     = (const int*)d_in[1];
    const int*   et     = (const int*)d_in[2];
    const int*   batch  = (const int*)d_in[3];
    const float* w_in   = (const float*)d_in[4];
    const float* b_in   = (const float*)d_in[5];
    const float* rel_w  = (const float*)d_in[6];
    const float* root_w = (const float*)d_in[7];
    const float* conv_b = (const float*)d_in[8];
    const float* bn_g   = (const float*)d_in[9];
    const float* bn_b   = (const float*)d_in[10];
    const float* w_out  = (const float*)d_in[11];
    const float* b_out  = (const float*)d_in[12];
    float* out = (float*)d_out;

    char* ws = (char*)d_ws;
    size_t off = 0;
    u16*   h_bf  = (u16*)(ws + off);  off += align256((size_t)N_NODES * H_DIM * 2);
    float* outb  = (float*)(ws + off); off += align256((size_t)N_NODES * H_DIM * 4);
    int*   off2  = (int*)(ws + off);  off += align256((size_t)(RN + 1) * 4 + 256);
    // ---- contiguous zero region: hist + bnA + bnB + pool + pcnt ----
    size_t zero_base = off;
    int*   hist  = (int*)(ws + off);  off += align256((size_t)RN * 4);
    float* bnA   = (float*)(ws + off); off += align256(2 * H_DIM * 4);
    float* bnB   = (float*)(ws + off); off += align256(2 * H_DIM * 4);
    float* pool  = (float*)(ws + off); off += align256((size_t)G_GRAPHS * H_DIM * 4);
    float* pcnt  = (float*)(ws + off); off += 256;
    size_t zero_len = off - zero_base;
    // ----
    int*   erank = (int*)(ws + off);  off += align256((size_t)E_EDGES * 4);
    int2*  e_pair = (int2*)(ws + off); off += align256((size_t)E_EDGES * 8 + 256);
    u16*   wp_in   = (u16*)(ws + off); off += align256((size_t)F_IN * H_DIM * 2);
    u16*   wp_root = (u16*)(ws + off); off += align256((size_t)L_LAYERS * H_DIM * H_DIM * 2);
    u16*   wp_rel  = (u16*)(ws + off); off += align256((size_t)L_LAYERS * R_REL * H_DIM * H_DIM * 2);
    int*   scan_part  = (int*)(ws + off); off += align256(2048 * 4);

    // ---- single memset for all zero-init buffers ----
    hipMemsetAsync(ws + zero_base, 0, zero_len, stream);

    // ---- preprocessing: histogram+rank -> scan -> atomic-free scatter ----
    count_kernel<<<1024, 256, 0, stream>>>(ei, et, hist, erank);
    const int NB = (RN + 1023) / 1024;                   // 1954
    scan1_kernel<<<NB, 256, 0, stream>>>(hist, off2, scan_part, RN);
    scan2_kernel<<<1, 256, 0, stream>>>(scan_part, NB);
    scan3_kernel<<<2048, 256, 0, stream>>>(off2, scan_part, RN);
    bucket_kernel<<<2048, 256, 0, stream>>>(ei, et, off2, erank, e_pair);

    // ---- pack all weights (one launch) ----
    pack_all<<<3 + L_LAYERS * R_REL, 256, 0, stream>>>(w_in, root_w, rel_w,
                                                       wp_in, wp_root, wp_rel);

    // ---- input MLP: h = relu(x @ w_in + b_in) -> bf16 (reads fp32 x) ----
    mfma_dense<F_IN, true, true, true, true><<<dim3(640), 256, 0, stream>>>(
        x, wp_in, b_in, h_bf, N_NODES);

    // ---- RGCN layers (barrier-free fused conv, 2-wave blocks) ----
    const int CONV_BLOCKS = (N_NODES + 31) / 32;   // 3125
    for (int l = 0; l < L_LAYERS; ++l) {
        float* bns = (l == 0) ? bnA : bnB;
        rgcn_conv<<<dim3(CONV_BLOCKS), 128, 0, stream>>>(
            h_bf, wp_rel + (size_t)l * R_REL * H_DIM * H_DIM,
            wp_root + (size_t)l * H_DIM * H_DIM, conv_b + (size_t)l * H_DIM,
            e_pair, off2, outb, bns);
        bn_apply<<<2048, 256, 0, stream>>>(outb, bns,
                                           bn_g + (size_t)l * H_DIM,
                                           bn_b + (size_t)l * H_DIM, h_bf);
    }

    // ---- global mean pool + classifier ----
    pool_kernel<<<512, 256, 0, stream>>>(h_bf, batch, pool, pcnt);
    logits_kernel<<<G_GRAPHS, 128, 0, stream>>>(pool, pcnt, w_out, b_out, out);
}

// Round 15
// 695.794 us; speedup vs baseline: 1.1246x; 1.0724x over previous
//
#include <hip/hip_runtime.h>

#define N_NODES 100000
#define E_EDGES 1600000
#define F_IN    64
#define H_DIM   128
#define R_REL   20
#define G_GRAPHS 64
#define C_CLASSES 10
#define L_LAYERS 2
#define BN_EPS  1e-5f
#define RN      (R_REL * N_NODES)   // 2,000,000 (rel,dst) bins

typedef unsigned short u16;
typedef unsigned int   u32;
typedef __attribute__((ext_vector_type(8))) short short8;
typedef __attribute__((ext_vector_type(4))) float f32x4;

static __device__ __forceinline__ float bf2f(u16 u) {
    u32 b = ((u32)u) << 16;
    return __builtin_bit_cast(float, b);
}
static __device__ __forceinline__ u16 f2bf(float f) {
    u32 x = __builtin_bit_cast(u32, f);
    u32 r = x + 0x7fff + ((x >> 16) & 1);   // RNE; inputs finite
    return (u16)(r >> 16);
}

// ============================================================
// Edge preprocessing: histogram+rank, scan, atomic-free scatter (R12, verified)
// ============================================================

__global__ void count_kernel(const int* __restrict__ ei, const int* __restrict__ et,
                             int* __restrict__ hist, int* __restrict__ erank) {
    for (int e = blockIdx.x * blockDim.x + threadIdx.x; e < E_EDGES;
         e += gridDim.x * blockDim.x) {
        int t = et[e];
        int d = ei[E_EDGES + e];
        erank[e] = atomicAdd(&hist[t * N_NODES + d], 1);
    }
}

__global__ void scan1_kernel(const int* __restrict__ in, int* __restrict__ out,
                             int* __restrict__ part, int n) {
    __shared__ int s[256];
    int t = threadIdx.x;
    int base = blockIdx.x * 1024;
    int v[4]; int sum = 0;
#pragma unroll
    for (int j = 0; j < 4; ++j) {
        int i = base + t * 4 + j;
        v[j] = (i < n) ? in[i] : 0;
        sum += v[j];
    }
    s[t] = sum;
    __syncthreads();
    for (int off = 1; off < 256; off <<= 1) {
        int x = (t >= off) ? s[t - off] : 0;
        __syncthreads();
        s[t] += x;
        __syncthreads();
    }
    if (t == 255) part[blockIdx.x] = s[255];
    int run = s[t] - sum;
#pragma unroll
    for (int j = 0; j < 4; ++j) {
        int i = base + t * 4 + j;
        if (i < n) out[i] = run;
        run += v[j];
    }
}

__global__ void scan2_kernel(int* __restrict__ part, int nb) {
    __shared__ int s[256];
    int t = threadIdx.x;
    int loc[8]; int sum = 0;
#pragma unroll
    for (int j = 0; j < 8; ++j) {
        int i = t * 8 + j;
        loc[j] = (i < nb) ? part[i] : 0;
        sum += loc[j];
    }
    s[t] = sum;
    __syncthreads();
    for (int off = 1; off < 256; off <<= 1) {
        int x = (t >= off) ? s[t - off] : 0;
        __syncthreads();
        s[t] += x;
        __syncthreads();
    }
    int run = s[t] - sum;
#pragma unroll
    for (int j = 0; j < 8; ++j) {
        int i = t * 8 + j;
        if (i < nb) part[i] = run;
        run += loc[j];
    }
}

__global__ void scan3_kernel(int* __restrict__ out, const int* __restrict__ part, int n) {
    for (int i = blockIdx.x * blockDim.x + threadIdx.x; i < n;
         i += gridDim.x * blockDim.x)
        out[i] += part[i >> 10];
    if (blockIdx.x == 0 && threadIdx.x == 0) out[n] = E_EDGES;
}

__global__ void bucket_kernel(const int* __restrict__ ei, const int* __restrict__ et,
                              const int* __restrict__ off2, const int* __restrict__ erank,
                              int2* __restrict__ epair) {
    for (int e = blockIdx.x * blockDim.x + threadIdx.x; e < E_EDGES;
         e += gridDim.x * blockDim.x) {
        int t = et[e];
        int s = ei[e];
        int d = ei[E_EDGES + e];
        epair[off2[t * N_NODES + d] + erank[e]] = make_int2(s, d);
    }
}

// ============================================================
// Weight pack (single launch): fp32 [K,128] -> bf16 MFMA-frag order
// ============================================================
__global__ void pack_all(const float* __restrict__ w_in, const float* __restrict__ root_w,
                         const float* __restrict__ rel_w, u16* __restrict__ wp_in,
                         u16* __restrict__ wp_root, u16* __restrict__ wp_rel) {
    int b = blockIdx.x;
    const float* w; u16* p; int K;
    if (b == 0)      { w = w_in;  p = wp_in;  K = F_IN; }
    else if (b <= 2) { w = root_w + (size_t)(b - 1) * H_DIM * H_DIM;
                       p = wp_root + (size_t)(b - 1) * H_DIM * H_DIM; K = H_DIM; }
    else             { w = rel_w + (size_t)(b - 3) * H_DIM * H_DIM;
                       p = wp_rel + (size_t)(b - 3) * H_DIM * H_DIM; K = H_DIM; }
    for (int o = threadIdx.x; o < K * H_DIM; o += blockDim.x) {
        int j  = o & 7;
        int l  = (o >> 3) & 63;
        int ct = (o >> 9) & 7;
        int kt = o >> 12;
        int k  = kt * 32 + (l >> 4) * 8 + j;
        int n  = ct * 16 + (l & 15);
        p[o] = f2bf(w[(size_t)k * H_DIM + n]);
    }
}

// ============================================================
// Dense MFMA GEMM (input MLP) — R2-R12 structure; INF32 stages fp32->bf16
// ============================================================
template<int K, bool INF32, bool RELU, bool HASBIAS, bool OUTBF16>
__global__ __launch_bounds__(256)
void mfma_dense(const void* __restrict__ Av, const u16* __restrict__ Wp,
                const float* __restrict__ bias, void* __restrict__ OutV, int M) {
    constexpr int CH = K / 8;
    __shared__ u16 Ws[K * H_DIM];
    __shared__ u16 As[64 * H_DIM];

    for (int o = threadIdx.x; o < K * H_DIM / 8; o += 256)
        ((short8*)Ws)[o] = ((const short8*)Wp)[o];

    const int lane = threadIdx.x & 63;
    const int wave = threadIdx.x >> 6;
    const int l15  = lane & 15;
    const int kgrp = lane >> 4;
    const int arow = wave * 16 + l15;

    for (int tb = blockIdx.x * 64; tb < M; tb += gridDim.x * 64) {
        __syncthreads();
        for (int o = threadIdx.x; o < 64 * CH; o += 256) {
            int row = o / CH, cc = o % CH;
            int grow = tb + row;
            short8 v = {0,0,0,0,0,0,0,0};
            if (grow < M) {
                if (INF32) {
                    const float* xf = (const float*)Av;
                    const float4* px = (const float4*)&xf[(size_t)grow * K + cc * 8];
                    float4 a = px[0], b = px[1];
                    v[0] = (short)f2bf(a.x); v[1] = (short)f2bf(a.y);
                    v[2] = (short)f2bf(a.z); v[3] = (short)f2bf(a.w);
                    v[4] = (short)f2bf(b.x); v[5] = (short)f2bf(b.y);
                    v[6] = (short)f2bf(b.z); v[7] = (short)f2bf(b.w);
                } else {
                    v = *(const short8*)&((const u16*)Av)[(size_t)grow * K + cc * 8];
                }
            }
            *(short8*)&As[row * K + ((cc ^ (row & 7)) * 8)] = v;
        }
        __syncthreads();

        f32x4 acc[8];
#pragma unroll
        for (int i = 0; i < 8; ++i) {
            acc[i][0] = 0.f; acc[i][1] = 0.f; acc[i][2] = 0.f; acc[i][3] = 0.f;
        }
#pragma unroll
        for (int kt = 0; kt < K / 32; ++kt) {
            short8 af = *(const short8*)&As[arow * K + (((kt * 4 + kgrp) ^ (arow & 7)) * 8)];
#pragma unroll
            for (int ct = 0; ct < 8; ++ct) {
                short8 bf = *(const short8*)&Ws[(((kt * 8 + ct) * 64) + lane) * 8];
                acc[ct] = __builtin_amdgcn_mfma_f32_16x16x32_bf16(af, bf, acc[ct], 0, 0, 0);
            }
        }

        if (OUTBF16) {
            __syncthreads();
#pragma unroll
            for (int ct = 0; ct < 8; ++ct) {
#pragma unroll
                for (int r = 0; r < 4; ++r) {
                    int row = wave * 16 + kgrp * 4 + r;
                    int col = ct * 16 + l15;
                    float v = acc[ct][r];
                    if (HASBIAS) v += bias[col];
                    if (RELU)    v = fmaxf(v, 0.f);
                    As[row * H_DIM + ((((col >> 3) ^ (row & 7)) << 3) | (col & 7))] = f2bf(v);
                }
            }
            __syncthreads();
            u16* Out = (u16*)OutV;
            for (int o = threadIdx.x; o < 64 * 16; o += 256) {
                int row = o >> 4, cc = o & 15;
                int grow = tb + row;
                if (grow < M)
                    *(short8*)&Out[(size_t)grow * H_DIM + cc * 8] =
                        *(const short8*)&As[row * H_DIM + ((cc ^ (row & 7)) << 3)];
            }
        } else {
            float* Out = (float*)OutV;
#pragma unroll
            for (int ct = 0; ct < 8; ++ct) {
#pragma unroll
                for (int r = 0; r < 4; ++r) {
                    int grow = tb + wave * 16 + kgrp * 4 + r;
                    if (grow < M) {
                        float v = acc[ct][r];
                        if (HASBIAS) v += bias[ct * 16 + l15];
                        if (RELU)    v = fmaxf(v, 0.f);
                        Out[(size_t)grow * H_DIM + ct * 16 + l15] = v;
                    }
                }
            }
        }
    }
}

// ============================================================
// Fused RGCN conv — R12 geometry (measured optimum: 251 µs, 40% occ):
// barrier-free relation loop, block = 64 dsts, 4 waves, wave-private
// 16-row Abf stripes, B-fragments direct from global (L2-hot),
// per-wave empty-segment skip, BN sum/sumsq fused in epilogue.
// ============================================================
__global__ __launch_bounds__(256, 4)
void rgcn_conv(const u16* __restrict__ h, const u16* __restrict__ Wrel,
               const u16* __restrict__ Wroot, const float* __restrict__ bias,
               const int2* __restrict__ epair, const int* __restrict__ off2,
               float* __restrict__ outb, float* __restrict__ bn_sums) {
    __shared__ int offs[R_REL][65];
    __shared__ u16 Abf[64 * H_DIM];        // 16 KB; wave-private 16-row stripes
    __shared__ float bnS[H_DIM], bnSS[H_DIM];

    const int d0 = blockIdx.x * 64;
    for (int i = threadIdx.x; i < R_REL * 65; i += 256) {
        int r = i / 65, j = i % 65;
        offs[r][j] = off2[r * N_NODES + min(d0 + j, N_NODES)];
    }
    if (threadIdx.x < H_DIM) { bnS[threadIdx.x] = 0.f; bnSS[threadIdx.x] = 0.f; }

    const int lane = threadIdx.x & 63;
    const int wv   = threadIdx.x >> 6;     // 0..3
    const int l15  = lane & 15;
    const int kgrp = lane >> 4;
    const int arow = wv * 16 + l15;        // 0..63
    const u32* h2  = (const u32*)h;
    u32* Ab32 = (u32*)Abf;

    f32x4 acc[8];
#pragma unroll
    for (int i = 0; i < 8; ++i) {
        acc[i][0] = 0.f; acc[i][1] = 0.f; acc[i][2] = 0.f; acc[i][3] = 0.f;
    }

    auto flushrow = [&](int dcur, int cnt, float f0, float f1) {
        float nm = 1.0f / (float)cnt;
        int dr = dcur - d0;
        u32 pk = (u32)f2bf(f0 * nm) | ((u32)f2bf(f1 * nm) << 16);
        Ab32[dr * 64 + ((((lane >> 2) ^ (dr & 7)) << 2) | (lane & 3))] = pk;
    };

    __syncthreads();      // offs + bnS init visible (only barrier before epilogue)

    for (int r = 0; r < R_REL; ++r) {
        const int estart = __builtin_amdgcn_readfirstlane(offs[r][wv * 16]);
        const int eend   = __builtin_amdgcn_readfirstlane(offs[r][wv * 16 + 16]);
        if (eend <= estart) continue;      // wave-private skip

        // zero my stripe (wave-local)
#pragma unroll
        for (int i = 0; i < 16; ++i)
            Ab32[(wv * 16 + i) * 64 + lane] = 0u;

        // ---- 16-deep batched gather + run-length flush ----
        {
            const int last = eend - 1;
            int ss[16], dd[16];
            u32 rv[16];
#pragma unroll
            for (int j = 0; j < 16; ++j) {
                int2 pr = epair[min(estart + j, last)];
                ss[j] = pr.x; dd[j] = pr.y;
            }
#pragma unroll
            for (int j = 0; j < 16; ++j)
                rv[j] = h2[(size_t)ss[j] * 64 + lane];

            int dcur = -1, cnt = 0;
            float f0 = 0.f, f1 = 0.f;
#pragma unroll
            for (int j = 0; j < 16; ++j) {
                if (estart + j < eend) {                 // wave-uniform
                    if (dd[j] != dcur) {
                        if (dcur >= 0) flushrow(dcur, cnt, f0, f1);
                        dcur = dd[j]; f0 = 0.f; f1 = 0.f; cnt = 0;
                    }
                    f0 += bf2f((u16)(rv[j] & 0xffff));
                    f1 += bf2f((u16)(rv[j] >> 16));
                    cnt++;
                }
            }
            // overflow batches (segment > 16 edges)
            for (int e = estart + 16; e < eend; e += 16) {
                int ss2[16], dd2[16];
                u32 rv2[16];
#pragma unroll
                for (int j = 0; j < 16; ++j) {
                    int2 pr = epair[min(e + j, last)];
                    ss2[j] = pr.x; dd2[j] = pr.y;
                }
#pragma unroll
                for (int j = 0; j < 16; ++j)
                    rv2[j] = h2[(size_t)ss2[j] * 64 + lane];
#pragma unroll
                for (int j = 0; j < 16; ++j) {
                    if (e + j < eend) {
                        if (dd2[j] != dcur) {
                            if (dcur >= 0) flushrow(dcur, cnt, f0, f1);
                            dcur = dd2[j]; f0 = 0.f; f1 = 0.f; cnt = 0;
                        }
                        f0 += bf2f((u16)(rv2[j] & 0xffff));
                        f1 += bf2f((u16)(rv2[j] >> 16));
                        cnt++;
                    }
                }
            }
            if (dcur >= 0) flushrow(dcur, cnt, f0, f1);
        }

        // ---- MFMA: A from my LDS stripe, B direct from global (L2-hot) ----
        const u16* Wr = Wrel + (size_t)r * H_DIM * H_DIM;
#pragma unroll
        for (int kt = 0; kt < 4; ++kt) {
            short8 af = *(const short8*)&Abf[arow * H_DIM + (((kt * 4 + kgrp) ^ (arow & 7)) * 8)];
#pragma unroll
            for (int ct = 0; ct < 8; ++ct) {
                short8 bf = *(const short8*)&Wr[(((kt * 8 + ct) * 64) + lane) * 8];
                acc[ct] = __builtin_amdgcn_mfma_f32_16x16x32_bf16(af, bf, acc[ct], 0, 0, 0);
            }
        }
    }

    // ---- root "relation": dense A = h rows direct from global ----
    {
        const int hrow = min(d0 + arow, N_NODES - 1);
#pragma unroll
        for (int kt = 0; kt < 4; ++kt) {
            short8 af = *(const short8*)&h[(size_t)hrow * H_DIM + kt * 32 + kgrp * 8];
#pragma unroll
            for (int ct = 0; ct < 8; ++ct) {
                short8 bf = *(const short8*)&Wroot[(((kt * 8 + ct) * 64) + lane) * 8];
                acc[ct] = __builtin_amdgcn_mfma_f32_16x16x32_bf16(af, bf, acc[ct], 0, 0, 0);
            }
        }
    }

    // ---- epilogue: outb = acc + bias; fused BN sum/sumsq ----
#pragma unroll
    for (int ct = 0; ct < 8; ++ct) {
        float bv = bias[ct * 16 + l15];
        float sl = 0.f, sq = 0.f;
#pragma unroll
        for (int rr = 0; rr < 4; ++rr) {
            int grow = d0 + wv * 16 + kgrp * 4 + rr;
            if (grow < N_NODES) {
                float v = acc[ct][rr] + bv;
                outb[(size_t)grow * H_DIM + ct * 16 + l15] = v;
                sl += v;
                sq += v * v;
            }
        }
        sl += __shfl_xor(sl, 16); sl += __shfl_xor(sl, 32);
        sq += __shfl_xor(sq, 16); sq += __shfl_xor(sq, 32);
        if (kgrp == 0) {
            atomicAdd(&bnS[ct * 16 + l15], sl);
            atomicAdd(&bnSS[ct * 16 + l15], sq);
        }
    }
    __syncthreads();
    if (threadIdx.x < H_DIM) {
        atomicAdd(&bn_sums[threadIdx.x], bnS[threadIdx.x]);
        atomicAdd(&bn_sums[H_DIM + threadIdx.x], bnSS[threadIdx.x]);
    }
}

// ============================================================
// BatchNorm apply + ReLU -> bf16 h
// ============================================================
__global__ void bn_apply(const float* __restrict__ X, const float* __restrict__ sums,
                         const float* __restrict__ gg, const float* __restrict__ bb,
                         u16* __restrict__ Hout) {
    __shared__ float sc[H_DIM], sh[H_DIM];
    if (threadIdx.x < H_DIM) {
        float mean = sums[threadIdx.x] * (1.0f / N_NODES);
        float var  = sums[H_DIM + threadIdx.x] * (1.0f / N_NODES) - mean * mean;
        float inv  = rsqrtf(var + BN_EPS) * gg[threadIdx.x];
        sc[threadIdx.x] = inv;
        sh[threadIdx.x] = bb[threadIdx.x] - mean * inv;
    }
    __syncthreads();
    int total = N_NODES * (H_DIM / 4);
    for (int idx = blockIdx.x * 256 + threadIdx.x; idx < total; idx += gridDim.x * 256) {
        float4 v = ((const float4*)X)[idx];
        int c = (idx & 31) << 2;
        ushort4 o;
        o.x = f2bf(fmaxf(v.x * sc[c + 0] + sh[c + 0], 0.f));
        o.y = f2bf(fmaxf(v.y * sc[c + 1] + sh[c + 1], 0.f));
        o.z = f2bf(fmaxf(v.z * sc[c + 2] + sh[c + 2], 0.f));
        o.w = f2bf(fmaxf(v.w * sc[c + 3] + sh[c + 3], 0.f));
        ((ushort4*)Hout)[idx] = o;
    }
}

// ============================================================
// Pool + classifier
// ============================================================
__global__ void pool_kernel(const u16* __restrict__ Hf, const int* __restrict__ batch,
                            float* __restrict__ pool, float* __restrict__ pcnt) {
    int col  = threadIdx.x & 127;
    int half = threadIdx.x >> 7;
    int chunk = (N_NODES + gridDim.x - 1) / gridDim.x;
    int start = blockIdx.x * chunk;
    int end   = min(N_NODES, start + chunk);
    int curg = -1;
    float acc = 0.f, c = 0.f;
    for (int row = start + half; row < end; row += 2) {
        int g = batch[row];
        if (g != curg) {
            if (curg >= 0) {
                atomicAdd(&pool[curg * H_DIM + col], acc);
                if (col == 0) atomicAdd(&pcnt[curg], c);
            }
            curg = g; acc = 0.f; c = 0.f;
        }
        acc += bf2f(Hf[(size_t)row * H_DIM + col]);
        c += 1.f;
    }
    if (curg >= 0) {
        atomicAdd(&pool[curg * H_DIM + col], acc);
        if (col == 0) atomicAdd(&pcnt[curg], c);
    }
}

__global__ void logits_kernel(const float* __restrict__ pool, const float* __restrict__ pcnt,
                              const float* __restrict__ w_out, const float* __restrict__ b_out,
                              float* __restrict__ out) {
    int g = blockIdx.x;
    __shared__ float p[H_DIM];
    float cnt = fmaxf(pcnt[g], 1.0f);
    p[threadIdx.x] = pool[g * H_DIM + threadIdx.x] / cnt;
    __syncthreads();
    if (threadIdx.x < C_CLASSES) {
        float acc = b_out[threadIdx.x];
        for (int k = 0; k < H_DIM; ++k)
            acc += p[k] * w_out[k * C_CLASSES + threadIdx.x];
        out[g * C_CLASSES + threadIdx.x] = 1.0f / (1.0f + expf(-acc));
    }
}

// ============================================================
// Host launch
// ============================================================
static inline size_t align256(size_t x) { return (x + 255) & ~(size_t)255; }

extern "C" void kernel_launch(void* const* d_in, const int* in_sizes, int n_in,
                              void* d_out, int out_size, void* d_ws, size_t ws_size,
                              hipStream_t stream) {
    const float* x      = (const float*)d_in[0];
    const int*   ei     = (const int*)d_in[1];
    const int*   et     = (const int*)d_in[2];
    const int*   batch  = (const int*)d_in[3];
    const float* w_in   = (const float*)d_in[4];
    const float* b_in   = (const float*)d_in[5];
    const float* rel_w  = (const float*)d_in[6];
    const float* root_w = (const float*)d_in[7];
    const float* conv_b = (const float*)d_in[8];
    const float* bn_g   = (const float*)d_in[9];
    const float* bn_b   = (const float*)d_in[10];
    const float* w_out  = (const float*)d_in[11];
    const float* b_out  = (const float*)d_in[12];
    float* out = (float*)d_out;

    char* ws = (char*)d_ws;
    size_t off = 0;
    u16*   h_bf  = (u16*)(ws + off);  off += align256((size_t)N_NODES * H_DIM * 2);
    float* outb  = (float*)(ws + off); off += align256((size_t)N_NODES * H_DIM * 4);
    int*   off2  = (int*)(ws + off);  off += align256((size_t)(RN + 1) * 4 + 256);
    // ---- contiguous zero region: hist + bnA + bnB + pool + pcnt ----
    size_t zero_base = off;
    int*   hist  = (int*)(ws + off);  off += align256((size_t)RN * 4);
    float* bnA   = (float*)(ws + off); off += align256(2 * H_DIM * 4);
    float* bnB   = (float*)(ws + off); off += align256(2 * H_DIM * 4);
    float* pool  = (float*)(ws + off); off += align256((size_t)G_GRAPHS * H_DIM * 4);
    float* pcnt  = (float*)(ws + off); off += 256;
    size_t zero_len = off - zero_base;
    // ----
    int*   erank = (int*)(ws + off);  off += align256((size_t)E_EDGES * 4);
    int2*  e_pair = (int2*)(ws + off); off += align256((size_t)E_EDGES * 8 + 256);
    u16*   wp_in   = (u16*)(ws + off); off += align256((size_t)F_IN * H_DIM * 2);
    u16*   wp_root = (u16*)(ws + off); off += align256((size_t)L_LAYERS * H_DIM * H_DIM * 2);
    u16*   wp_rel  = (u16*)(ws + off); off += align256((size_t)L_LAYERS * R_REL * H_DIM * H_DIM * 2);
    int*   scan_part  = (int*)(ws + off); off += align256(2048 * 4);

    // ---- single memset for all zero-init buffers ----
    hipMemsetAsync(ws + zero_base, 0, zero_len, stream);

    // ---- preprocessing: histogram+rank -> scan -> atomic-free scatter ----
    count_kernel<<<1024, 256, 0, stream>>>(ei, et, hist, erank);
    const int NB = (RN + 1023) / 1024;                   // 1954
    scan1_kernel<<<NB, 256, 0, stream>>>(hist, off2, scan_part, RN);
    scan2_kernel<<<1, 256, 0, stream>>>(scan_part, NB);
    scan3_kernel<<<2048, 256, 0, stream>>>(off2, scan_part, RN);
    bucket_kernel<<<2048, 256, 0, stream>>>(ei, et, off2, erank, e_pair);

    // ---- pack all weights (one launch) ----
    pack_all<<<3 + L_LAYERS * R_REL, 256, 0, stream>>>(w_in, root_w, rel_w,
                                                       wp_in, wp_root, wp_rel);

    // ---- input MLP: h = relu(x @ w_in + b_in) -> bf16 (reads fp32 x) ----
    mfma_dense<F_IN, true, true, true, true><<<dim3(640), 256, 0, stream>>>(
        x, wp_in, b_in, h_bf, N_NODES);

    // ---- RGCN layers (barrier-free fused conv, R12 geometry) ----
    const int CONV_BLOCKS = (N_NODES + 63) / 64;   // 1563
    for (int l = 0; l < L_LAYERS; ++l) {
        float* bns = (l == 0) ? bnA : bnB;
        rgcn_conv<<<dim3(CONV_BLOCKS), 256, 0, stream>>>(
            h_bf, wp_rel + (size_t)l * R_REL * H_DIM * H_DIM,
            wp_root + (size_t)l * H_DIM * H_DIM, conv_b + (size_t)l * H_DIM,
            e_pair, off2, outb, bns);
        bn_apply<<<2048, 256, 0, stream>>>(outb, bns,
                                           bn_g + (size_t)l * H_DIM,
                                           bn_b + (size_t)l * H_DIM, h_bf);
    }

    // ---- global mean pool + classifier ----
    pool_kernel<<<512, 256, 0, stream>>>(h_bf, batch, pool, pcnt);
    logits_kernel<<<G_GRAPHS, 128, 0, stream>>>(pool, pcnt, w_out, b_out, out);
}